// Round 4
// baseline (558.178 us; speedup 1.0000x reference)
//
#include <hip/hip_runtime.h>

// FourierFilter: per-(b,c) rfft-4096 -> top-k (80% energy) spectral mask -> irfft.
// x:[32,4096,128] f32. out = concat(x_var, x_inv), each [32,4096,128].
// SINGLE FUSED KERNEL: block = (b, channel-pair), 512 threads = 2 x 256-thread groups,
// each group runs the packed-real FFT-2048 pipeline for one channel in its own LDS arrays.
// Loads/stores go straight to x / xvar / xinv (strided float2; memory-side L3 absorbs the
// cross-block line sharing and merges partial-line writes). No transposes, no workspace.

#define TLEN 4096
#define N2   2048
#define CCH  128
#define BB   32
#define HALF 16777216  // 32*4096*128
#define PI_F 3.14159265358979323846f
#define ARR  2113      // LP(2048)=2112 max index

// LDS pad swizzle for FFT arrays
#define LP(i) ((i) + ((i) >> 5))

__device__ __forceinline__ void cmul(float& r, float& i, float br, float bi) {
  float tr = r * br - i * bi;
  i = r * bi + i * br;
  r = tr;
}

__device__ __forceinline__ void dft4(float vr[4], float vi[4], float s) {
  float t0r = vr[0] + vr[2], t0i = vi[0] + vi[2];
  float t1r = vr[0] - vr[2], t1i = vi[0] - vi[2];
  float t2r = vr[1] + vr[3], t2i = vi[1] + vi[3];
  float d3r = vr[1] - vr[3], d3i = vi[1] - vi[3];
  float t3r = -s * d3i, t3i = s * d3r;
  vr[0] = t0r + t2r; vi[0] = t0i + t2i;
  vr[1] = t1r + t3r; vi[1] = t1i + t3i;
  vr[2] = t0r - t2r; vi[2] = t0i - t2i;
  vr[3] = t1r - t3r; vi[3] = t1i - t3i;
}

__device__ __forceinline__ void dft8(float vr[8], float vi[8], float s) {
  float er[4]  = {vr[0], vr[2], vr[4], vr[6]};
  float ei[4]  = {vi[0], vi[2], vi[4], vi[6]};
  float odr[4] = {vr[1], vr[3], vr[5], vr[7]};
  float odi[4] = {vi[1], vi[3], vi[5], vi[7]};
  dft4(er, ei, s);
  dft4(odr, odi, s);
  const float c = 0.70710678118654752440f;
  float wr[4] = {1.0f, c, 0.0f, -c};
  float wi[4] = {0.0f, s * c, s, s * c};
  #pragma unroll
  for (int k = 0; k < 4; ++k) {
    float tr = wr[k] * odr[k] - wi[k] * odi[k];
    float ti = wr[k] * odi[k] + wi[k] * odr[k];
    vr[k]     = er[k] + tr; vi[k]     = ei[k] + ti;
    vr[k + 4] = er[k] - tr; vi[k + 4] = ei[k] - ti;
  }
}

// Stockham radix-8, Ns=1: twiddles all 1. 256 threads per channel group, j=ctid.
__device__ __forceinline__ void stage8_first(float* zr, float* zi, int ctid, float s) {
  float vr[8], vi[8];
  #pragma unroll
  for (int r = 0; r < 8; ++r) {
    int idx = LP(ctid + (r << 8));
    vr[r] = zr[idx]; vi[r] = zi[idx];
  }
  dft8(vr, vi, s);
  __syncthreads();
  #pragma unroll
  for (int r = 0; r < 8; ++r) {
    int idx = LP((ctid << 3) + r);
    zr[idx] = vr[r]; zi[idx] = vi[r];
  }
  __syncthreads();
}

template <int NS>
__device__ __forceinline__ void stage8_tw(float* zr, float* zi, int ctid, float s) {
  int j = ctid;
  int p = j & (NS - 1);
  float vr[8], vi[8];
  #pragma unroll
  for (int r = 0; r < 8; ++r) {
    int idx = LP(j + (r << 8));
    vr[r] = zr[idx]; vi[r] = zi[idx];
  }
  float ang = s * 6.28318530717958647692f * (float)p / (float)(NS * 8);
  float s1, c1; __sincosf(ang, &s1, &c1);
  float c2 = c1 * c1 - s1 * s1, s2 = 2.0f * c1 * s1;
  float c3 = c2 * c1 - s2 * s1, s3 = c2 * s1 + s2 * c1;
  float c4 = c2 * c2 - s2 * s2, s4 = 2.0f * c2 * s2;
  float c5 = c4 * c1 - s4 * s1, s5 = c4 * s1 + s4 * c1;
  float c6 = c4 * c2 - s4 * s2, s6 = c4 * s2 + s4 * c2;
  float c7 = c4 * c3 - s4 * s3, s7 = c4 * s3 + s4 * c3;
  cmul(vr[1], vi[1], c1, s1);
  cmul(vr[2], vi[2], c2, s2);
  cmul(vr[3], vi[3], c3, s3);
  cmul(vr[4], vi[4], c4, s4);
  cmul(vr[5], vi[5], c5, s5);
  cmul(vr[6], vi[6], c6, s6);
  cmul(vr[7], vi[7], c7, s7);
  dft8(vr, vi, s);
  __syncthreads();
  int idxD = ((j - p) << 3) + p;
  #pragma unroll
  for (int r = 0; r < 8; ++r) {
    int idx = LP(idxD + r * NS);
    zr[idx] = vr[r]; zi[idx] = vi[r];
  }
  __syncthreads();
}

__device__ __forceinline__ void stage4_last(float* zr, float* zi, int ctid, float s) {
  #pragma unroll
  for (int half = 0; half < 2; ++half) {
    int j = ctid + (half << 8);
    float ang = s * PI_F * (float)j * (1.0f / 1024.0f);
    float s1, c1; __sincosf(ang, &s1, &c1);
    float c2 = c1 * c1 - s1 * s1, s2 = 2.0f * c1 * s1;
    float c3 = c2 * c1 - s2 * s1, s3 = c2 * s1 + s2 * c1;
    float vr[4], vi[4];
    #pragma unroll
    for (int r = 0; r < 4; ++r) {
      int idx = LP(j + (r << 9));
      vr[r] = zr[idx]; vi[r] = zi[idx];
    }
    cmul(vr[1], vi[1], c1, s1);
    cmul(vr[2], vi[2], c2, s2);
    cmul(vr[3], vi[3], c3, s3);
    dft4(vr, vi, s);
    #pragma unroll
    for (int r = 0; r < 4; ++r) {
      int idx = LP(j + (r << 9));
      zr[idx] = vr[r]; zi[idx] = vi[r];
    }
  }
  __syncthreads();
}

__device__ __forceinline__ void fft2048(float* zr, float* zi, int ctid, float s) {
  stage8_first(zr, zi, ctid, s);
  stage8_tw<8>(zr, zi, ctid, s);
  stage8_tw<64>(zr, zi, ctid, s);
  stage4_last(zr, zi, ctid, s);
}

// Per-channel-group (256 thr) reduction of 1 value; red layout [ch][bank][wave].
__device__ __forceinline__ float block_sum1(float v, float* red, int tid, int ch, int bank) {
  #pragma unroll
  for (int o = 32; o > 0; o >>= 1) v += __shfl_down(v, o, 64);
  if ((tid & 63) == 0) red[((ch << 1) + bank) * 4 + ((tid >> 6) & 3)] = v;
  __syncthreads();
  const float* bp = red + ((ch << 1) + bank) * 4;
  return bp[0] + bp[1] + bp[2] + bp[3];
}

// Per-channel-group reduction of 3 values; red3 layout [ch][bank][wave][3].
__device__ __forceinline__ void block_sum3(float v[3], float* red3, int tid, int ch, int bank) {
  #pragma unroll
  for (int o = 32; o > 0; o >>= 1) {
    v[0] += __shfl_down(v[0], o, 64);
    v[1] += __shfl_down(v[1], o, 64);
    v[2] += __shfl_down(v[2], o, 64);
  }
  if ((tid & 63) == 0) {
    float* sp = red3 + (((ch << 1) + bank) * 4 + ((tid >> 6) & 3)) * 3;
    sp[0] = v[0]; sp[1] = v[1]; sp[2] = v[2];
  }
  __syncthreads();
  const float* bp = red3 + ((ch << 1) + bank) * 12;
  v[0] = bp[0] + bp[3] + bp[6] + bp[9];
  v[1] = bp[1] + bp[4] + bp[7] + bp[10];
  v[2] = bp[2] + bp[5] + bp[8] + bp[11];
}

// One block per (b, channel-pair). 512 threads = 2 channel groups x 256.
__global__ __launch_bounds__(512) void fourier_fused(const float* __restrict__ x,
                                                     float* __restrict__ xvar,
                                                     float* __restrict__ xinv) {
  __shared__ float zr[2][ARR], zi[2][ARR];
  __shared__ float red1[16];       // [ch][bank][wave]
  __shared__ float red3[48];       // [ch][bank][wave][3]
  int tid = threadIdx.x;
  int cg = blockIdx.x, b = blockIdx.y;
  int ch = tid >> 8, ctid = tid & 255;
  float* Zr = zr[ch];
  float* Zi = zi[ch];

  const float* xp = x + (size_t)b * TLEN * CCH + 2 * cg;

  // ---- Load: lane reads float2 {ch0,ch1} at time t; packed z[k] = x[2k] + i*x[2k+1] ----
  #pragma unroll
  for (int i = 0; i < 8; ++i) {
    int t = (i << 9) + tid;
    float2 v = *(const float2*)(xp + (size_t)t * CCH);
    int k = t >> 1;
    float* base = (t & 1) ? zi[0] : zr[0];
    base[LP(k)] = v.x;
    base[ARR + LP(k)] = v.y;
  }
  __syncthreads();

  fft2048(Zr, Zi, ctid, -1.0f);   // forward

  // ---- Unpack to rfft bins X[0..2048] IN PLACE (per-thread pairs (k,2048-k)) ----
  float eb[9];
  eb[8] = 0.0f;
  const float RC  = 0.92387953251128675613f;   // cos(pi/8)
  const float RSn = -0.38268343236508977173f;  // -sin(pi/8)
  float ws, wc;
  __sincosf(-PI_F * (float)ctid * (1.0f / 2048.0f), &ws, &wc);
  #pragma unroll
  for (int jj = 0; jj < 4; ++jj) {
    int k = ctid + (jj << 8);
    int mkz = (N2 - k) & (N2 - 1);
    int ik = LP(k), im = LP(N2 - k);
    float akr = Zr[ik],      aki = Zi[ik];
    float bkr = Zr[LP(mkz)], bki = Zi[LP(mkz)];
    float Er  = 0.5f * (akr + bkr);
    float Ei  = 0.5f * (aki - bki);
    float Or_ = 0.5f * (aki + bki);
    float Oi  = 0.5f * (bkr - akr);
    float tr = wc * Or_ - ws * Oi;
    float ti = wc * Oi + ws * Or_;
    float x0r = Er + tr, x0i = Ei + ti;
    float x1r = Er - tr, x1i = ti - Ei;
    Zr[ik] = x0r; Zi[ik] = x0i;
    Zr[im] = x1r; Zi[im] = x1i;
    eb[2 * jj]     = x0r * x0r + x0i * x0i;
    eb[2 * jj + 1] = x1r * x1r + x1i * x1i;
    float nwc = wc * RC - ws * RSn;
    ws = wc * RSn + ws * RC; wc = nwc;
  }
  if (ctid == 0) {                 // k=1024 self-pair: X[1024] = (Re, -Im)
    int i4 = LP(1024);
    float re = Zr[i4], im_ = Zi[i4];
    Zi[i4] = -im_;
    eb[8] = re * re + im_ * im_;
  }

  // ---- Selection: tau = max tau s.t. sum(e >= tau) > 0.8*total ----
  float tloc = 0.0f;
  #pragma unroll
  for (int s = 0; s < 9; ++s) tloc += eb[s];
  float total = block_sum1(tloc, red1, tid, ch, 0);
  float thresh = 0.8f * total;

  // Quaternary bisection on float bit patterns: 3 candidates/iter, 16 iters (4^16 = 2^32).
  unsigned lo = 0u, hi = 0x7F7FFFFFu;
  for (int it = 0; it < 16; ++it) {
    unsigned span = hi - lo;
    unsigned q = span >> 2;
    unsigned m1 = lo + (q ? q : 1u);
    unsigned m2 = lo + (q ? (q << 1) : 2u);
    unsigned m3 = lo + (q ? (q * 3u) : 3u);
    m1 = m1 > hi ? hi : m1;
    m2 = m2 > hi ? hi : m2;
    m3 = m3 > hi ? hi : m3;
    float t1 = __uint_as_float(m1), t2 = __uint_as_float(m2), t3 = __uint_as_float(m3);
    float v[3] = {0.0f, 0.0f, 0.0f};
    #pragma unroll
    for (int s = 0; s < 9; ++s) {
      float e = eb[s];
      v[0] += (e >= t1) ? e : 0.0f;
      v[1] += (e >= t2) ? e : 0.0f;
      v[2] += (e >= t3) ? e : 0.0f;
    }
    block_sum3(v, red3, tid, ch, (it + 1) & 1);
    if (v[2] > thresh)      { lo = m3; }
    else if (v[1] > thresh) { lo = m2; hi = m3 - 1u; }
    else if (v[0] > thresh) { lo = m1; hi = m2 - 1u; }
    else                    { hi = m1 - 1u; }
  }
  float tau = __uint_as_float(lo);

  // ---- Mask + hermitian repack IN PLACE ----
  const float RSp = 0.38268343236508977173f;
  __sincosf(PI_F * (float)ctid * (1.0f / 2048.0f), &ws, &wc);
  #pragma unroll
  for (int jj = 0; jj < 4; ++jj) {
    int k = ctid + (jj << 8);
    int ik = LP(k), im = LP(N2 - k);
    float xkr = Zr[ik], xki = Zi[ik];
    float xmr = Zr[im], xmi = Zi[im];
    float ekk = xkr * xkr + xki * xki;
    float emm = xmr * xmr + xmi * xmi;
    if (ekk >= tau) { xkr = 0.0f; xki = 0.0f; }
    if (emm >= tau) { xmr = 0.0f; xmi = 0.0f; }
    float Er = 0.5f * (xkr + xmr);
    float Ei = 0.5f * (xki - xmi);
    float Br = 0.5f * (xkr - xmr);
    float Bi = 0.5f * (xki + xmi);
    float Or_ = wc * Br - ws * Bi;
    float Oi  = wc * Bi + ws * Br;
    Zr[ik] = Er - Oi;  Zi[ik] = Ei + Or_;
    Zr[im] = Er + Oi;  Zi[im] = Or_ - Ei;   // k=0 writes slot 2048: outside iFFT range, harmless
    float nwc = wc * RC - ws * RSp;
    ws = wc * RSp + ws * RC; wc = nwc;
  }
  if (ctid == 0) {                 // k=1024: Z[1024] = conj(masked X[1024])
    int i4 = LP(1024);
    float re = Zr[i4], im_ = Zi[i4];
    float e = re * re + im_ * im_;
    if (e >= tau) { re = 0.0f; im_ = 0.0f; }
    Zr[i4] = re; Zi[i4] = -im_;
  }
  __syncthreads();

  fft2048(Zr, Zi, ctid, 1.0f);     // inverse (unscaled)

  // ---- Store: xvar from LDS, xinv = x - xvar (x re-read; L3-hot) ----
  const float scale = 1.0f / 2048.0f;
  float* vo = xvar + (size_t)b * TLEN * CCH + 2 * cg;
  float* io = xinv + (size_t)b * TLEN * CCH + 2 * cg;
  #pragma unroll
  for (int i = 0; i < 8; ++i) {
    int t = (i << 9) + tid;
    int k = t >> 1;
    const float* base = (t & 1) ? zi[0] : zr[0];
    float a0 = base[LP(k)] * scale;
    float a1 = base[ARR + LP(k)] * scale;
    float2 xv = *(const float2*)(xp + (size_t)t * CCH);
    float2 v0; v0.x = a0;        v0.y = a1;
    float2 v1; v1.x = xv.x - a0; v1.y = xv.y - a1;
    *(float2*)(vo + (size_t)t * CCH) = v0;
    *(float2*)(io + (size_t)t * CCH) = v1;
  }
}

extern "C" void kernel_launch(void* const* d_in, const int* in_sizes, int n_in,
                              void* d_out, int out_size, void* d_ws, size_t ws_size,
                              hipStream_t stream) {
  const float* x = (const float*)d_in[0];
  float* out  = (float*)d_out;
  float* xvar = out;
  float* xinv = out + HALF;

  dim3 grid(CCH / 2, BB);   // (64 channel-pairs, 32 batches)
  fourier_fused<<<grid, 512, 0, stream>>>(x, xvar, xinv);
}